// Round 3
// baseline (1048.325 us; speedup 1.0000x reference)
//
#include <hip/hip_runtime.h>

// VectorQuantizer: inputs [8,4096,64] f32, weight [8192,64] f32.
// Outputs concat: quantized_st [2097152] f32, loss [1] f32, indices [32768] f32.
//
// Strategy: fast fp32 top-2 argmin (split-K). Rows whose top-2 gap is within
// MARGIN are re-resolved with a bit-exact emulation of the numpy fp32
// reference comparator d = fl32(fl32(x2+w2) - 2*dot):
//   x2/w2: numpy pairwise 8-accumulator order; dot: sequential fp32 FMA
//   (OpenBLAS sgemm k-loop); tie -> lowest index (np.argmin first occurrence).

#define N_ROWS 32768
#define DIM 64
#define K_CODES 8192
#define KSPLIT 8
#define KCHUNK (K_CODES / KSPLIT)
#define OUT_Q 0
#define OUT_LOSS 2097152
#define OUT_IDX 2097153
#define MARGIN 1e-4f   // c-space flag band; decisive rows have gap < ~1.6e-5

// monotone float<->uint mapping (order-preserving)
__device__ __forceinline__ unsigned f2u_ord(float f) {
    unsigned u = __float_as_uint(f);
    return (u & 0x80000000u) ? ~u : (u | 0x80000000u);
}
__device__ __forceinline__ float u2f_ord(unsigned u) {
    unsigned v = (u & 0x80000000u) ? (u & 0x7fffffffu) : ~u;
    return __uint_as_float(v);
}

// numpy pairwise_sum over 64 squared elements, exact emulation.
// temp p[i] = fl(v[i]*v[i]); r[0..7]=p[0..7]; r[j]+=p[i+j] for i=8,16,..,56;
// res = ((r0+r1)+(r2+r3))+((r4+r5)+(r6+r7)).
__device__ __forceinline__ float np_pairwise_sq64(const float* v) {
    float r[8];
#pragma unroll
    for (int j = 0; j < 8; j++) r[j] = __fmul_rn(v[j], v[j]);
#pragma unroll
    for (int i = 8; i < 64; i += 8) {
#pragma unroll
        for (int j = 0; j < 8; j++)
            r[j] = __fadd_rn(r[j], __fmul_rn(v[i + j], v[i + j]));
    }
    return __fadd_rn(__fadd_rn(__fadd_rn(r[0], r[1]), __fadd_rn(r[2], r[3])),
                     __fadd_rn(__fadd_rn(r[4], r[5]), __fadd_rn(r[6], r[7])));
}

// ---------------- kernel 0: wsq[k] = ||w_k||^2, np-exact fp32 ----------------
__global__ __launch_bounds__(256) void vq_wsq(const float* __restrict__ weight,
                                              float* __restrict__ wsq) {
    int k = blockIdx.x * 256 + threadIdx.x;
    float w[64];
    const float4* wp = (const float4*)(weight + (size_t)k * DIM);
#pragma unroll
    for (int i = 0; i < 16; i++) {
        float4 t = wp[i];
        w[4 * i] = t.x; w[4 * i + 1] = t.y; w[4 * i + 2] = t.z; w[4 * i + 3] = t.w;
    }
    wsq[k] = np_pairwise_sq64(w);
}

// ---------------- kernel 1: per-(row,chunk) top-2 in c-space ----------------
// c(k) = wsq[k] - 2*dot(x,w_k)  (per-row ||x||^2 dropped; order-equivalent).
__global__ __launch_bounds__(256) void vq_argmin_top2(const float* __restrict__ inp,
                                                      const float* __restrict__ weight,
                                                      const float* __restrict__ wsq,
                                                      unsigned long long* __restrict__ bestk,
                                                      float* __restrict__ secd) {
    int row = blockIdx.x * 256 + threadIdx.x;
    int kbase = blockIdx.y * KCHUNK;

    float4 x[16];
    const float4* xp = (const float4*)(inp + (size_t)row * DIM);
#pragma unroll
    for (int i = 0; i < 16; i++) x[i] = xp[i];

    float best = 3.402823466e+38f;
    float sec  = 3.402823466e+38f;
    int bidx = kbase;

    for (int c = 0; c < KCHUNK; c++) {
        int code = kbase + c;
        const float4* wp = (const float4*)(weight + (size_t)code * DIM);
        float s0 = 0.f, s1 = 0.f, s2 = 0.f, s3 = 0.f;
#pragma unroll
        for (int i = 0; i < 16; i++) {
            float4 w = wp[i];
            s0 = fmaf(x[i].x, w.x, s0);
            s1 = fmaf(x[i].y, w.y, s1);
            s2 = fmaf(x[i].z, w.z, s2);
            s3 = fmaf(x[i].w, w.w, s3);
        }
        float s = (s0 + s1) + (s2 + s3);
        float d = fmaf(-2.f, s, wsq[code]);
        if (d < best) { sec = best; best = d; bidx = code; }
        else if (d < sec) { sec = d; }
    }

    unsigned long long key = ((unsigned long long)f2u_ord(best) << 32) | (unsigned)bidx;
    bestk[(size_t)blockIdx.y * N_ROWS + row] = key;
    secd [(size_t)blockIdx.y * N_ROWS + row] = sec;
}

// ---------------- kernel 2: merge chunks, flag near-ties ----------------
__global__ __launch_bounds__(256) void vq_merge(const unsigned long long* __restrict__ bestk,
                                                const float* __restrict__ secd,
                                                int* __restrict__ final_idx,
                                                int* __restrict__ recheck_rows,
                                                int* __restrict__ recheck_count) {
    int row = blockIdx.x * 256 + threadIdx.x;

    unsigned long long ks[KSPLIT];
#pragma unroll
    for (int c = 0; c < KSPLIT; c++) ks[c] = bestk[(size_t)c * N_ROWS + row];

    unsigned long long k1 = ks[0];
#pragma unroll
    for (int c = 1; c < KSPLIT; c++) k1 = (ks[c] < k1) ? ks[c] : k1;

    float d1 = u2f_ord((unsigned)(k1 >> 32));
    float d2 = 3.402823466e+38f;
#pragma unroll
    for (int c = 0; c < KSPLIT; c++) {
        if (ks[c] != k1) {
            float bd = u2f_ord((unsigned)(ks[c] >> 32));
            if (bd < d2) d2 = bd;
        }
        float sd = secd[(size_t)c * N_ROWS + row];
        if (sd < d2) d2 = sd;
    }

    final_idx[row] = (int)(k1 & 0xffffffffull);
    if (d2 - d1 < MARGIN) {
        int slot = atomicAdd(recheck_count, 1);
        recheck_rows[slot] = row;
    }
}

// ---------------- kernel 3: np-exact rescan of flagged rows ----------------
__global__ __launch_bounds__(256) void vq_recheck_np(const float* __restrict__ inp,
                                                     const float* __restrict__ weight,
                                                     const float* __restrict__ wsq,
                                                     const int* __restrict__ recheck_rows,
                                                     const int* __restrict__ recheck_count,
                                                     int* __restrict__ final_idx) {
    __shared__ float xs[DIM];
    __shared__ float x2s;
    __shared__ float rd[256];
    __shared__ int   ri[256];
    int tid = threadIdx.x;
    int cnt = *recheck_count;
    if (cnt > N_ROWS) cnt = N_ROWS;

    for (int li = blockIdx.x; li < cnt; li += gridDim.x) {
        int row = recheck_rows[li];
        if (tid < DIM) xs[tid] = inp[(size_t)row * DIM + tid];
        __syncthreads();
        if (tid == 0) x2s = np_pairwise_sq64(xs);
        __syncthreads();
        float x2 = x2s;

        float bd = 3.402823466e+38f;
        int bi = 0x7fffffff;
        for (int code = tid; code < K_CODES; code += 256) {
            const float* wp = weight + (size_t)code * DIM;
            // OpenBLAS sgemm semantics: sequential fp32 FMA over k in order
            float s = 0.f;
#pragma unroll
            for (int i = 0; i < DIM; i++) s = __builtin_fmaf(xs[i], wp[i], s);
            float t1 = __fadd_rn(x2, wsq[code]);
            float d  = __fsub_rn(t1, __fmul_rn(2.0f, s));
            if (d < bd) { bd = d; bi = code; }   // ascending codes: strict < = first occurrence
        }
        rd[tid] = bd; ri[tid] = bi;
        __syncthreads();
        for (int s = 128; s > 0; s >>= 1) {
            if (tid < s) {
                if (rd[tid + s] < rd[tid] ||
                    (rd[tid + s] == rd[tid] && ri[tid + s] < ri[tid])) {
                    rd[tid] = rd[tid + s]; ri[tid] = ri[tid + s];
                }
            }
            __syncthreads();
        }
        if (tid == 0) final_idx[row] = ri[0];
        __syncthreads();
    }
}

// ---------------- kernel 4: gather + STE + loss + index write ----------------
__global__ __launch_bounds__(256) void vq_final(const float* __restrict__ inp,
                                                const float* __restrict__ weight,
                                                const int* __restrict__ final_idx,
                                                float* __restrict__ out) {
    int gid = blockIdx.x * 256 + threadIdx.x;
    int row = gid >> 4;
    int sub = gid & 15;

    int idx = final_idx[row];

    float4 x = ((const float4*)inp)[gid];
    float4 w = ((const float4*)weight)[idx * 16 + sub];

    float4 q;
    q.x = x.x + (w.x - x.x);
    q.y = x.y + (w.y - x.y);
    q.z = x.z + (w.z - x.z);
    q.w = x.w + (w.w - x.w);
    ((float4*)(out + OUT_Q))[gid] = q;

    if (sub == 0) out[OUT_IDX + row] = (float)idx;

    float dx = w.x - x.x, dy = w.y - x.y, dz = w.z - x.z, dw = w.w - x.w;
    float lp = dx * dx + dy * dy + dz * dz + dw * dw;

#pragma unroll
    for (int o = 32; o > 0; o >>= 1) lp += __shfl_down(lp, o, 64);

    __shared__ float red[4];
    int wid = threadIdx.x >> 6;
    int lane = threadIdx.x & 63;
    if (lane == 0) red[wid] = lp;
    __syncthreads();
    if (threadIdx.x == 0) {
        float bs = red[0] + red[1] + red[2] + red[3];
        atomicAdd(out + OUT_LOSS, bs * (0.25f / 2097152.f));
    }
}

extern "C" void kernel_launch(void* const* d_in, const int* in_sizes, int n_in,
                              void* d_out, int out_size, void* d_ws, size_t ws_size,
                              hipStream_t stream) {
    const float* inp = (const float*)d_in[0];
    const float* weight = (const float*)d_in[1];
    float* out = (float*)d_out;

    char* ws = (char*)d_ws;
    unsigned long long* bestk = (unsigned long long*)ws;              // 2 MB
    float* secd      = (float*)(ws + (size_t)KSPLIT * N_ROWS * 8);    // 1 MB
    char*  p         = ws + (size_t)KSPLIT * N_ROWS * 12;
    int*   final_idx = (int*)p;                                       // 128 KB
    int*   rrows     = (int*)(p + (size_t)N_ROWS * 4);                // 128 KB
    int*   rcount    = (int*)(p + (size_t)N_ROWS * 8);                // 4 B
    float* wsq       = (float*)(p + (size_t)N_ROWS * 8 + 256);        // 32 KB

    hipMemsetAsync(rcount, 0, sizeof(int), stream);
    hipMemsetAsync(out + OUT_LOSS, 0, sizeof(float), stream);

    vq_wsq<<<K_CODES / 256, 256, 0, stream>>>(weight, wsq);
    vq_argmin_top2<<<dim3(N_ROWS / 256, KSPLIT), 256, 0, stream>>>(inp, weight, wsq, bestk, secd);
    vq_merge<<<N_ROWS / 256, 256, 0, stream>>>(bestk, secd, final_idx, rrows, rcount);
    vq_recheck_np<<<64, 256, 0, stream>>>(inp, weight, wsq, rrows, rcount, final_idx);
    vq_final<<<(N_ROWS * DIM / 4) / 256, 256, 0, stream>>>(inp, weight, final_idx, out);
}

// Round 4
// 273.389 us; speedup vs baseline: 3.8346x; 3.8346x over previous
//
#include <hip/hip_runtime.h>

// VectorQuantizer: inputs [8,4096,64] f32, weight [8192,64] f32.
// Outputs concat: quantized_st [2097152] f32, loss [1] f32, indices [32768] f32.
//
// R4: MFMA main pass. fp32 dot emulated via bf16 two-term split:
//   dot = xh*wh + xl*wh + xh*wl   (error <= ~1e-5 absolute in c-space)
// c(k) = wsq[k] - 2*dot. Per-lane top-2 + index, shuffle-reduced, then the
// proven split-K merge -> np-exact recheck of rows with gap < MARGIN.

typedef short bf16x8 __attribute__((ext_vector_type(8)));
typedef float f32x4  __attribute__((ext_vector_type(4)));

#define N_ROWS 32768
#define DIM 64
#define K_CODES 8192
#define KSPLIT 8
#define KCHUNK 1024
#define OUT_Q 0
#define OUT_LOSS 2097152
#define OUT_IDX 2097153
#define MARGIN 1e-4f

// ---- helpers ----
__device__ __forceinline__ unsigned f2u_ord(float f) {
    unsigned u = __float_as_uint(f);
    return (u & 0x80000000u) ? ~u : (u | 0x80000000u);
}
__device__ __forceinline__ float u2f_ord(unsigned u) {
    unsigned v = (u & 0x80000000u) ? (u & 0x7fffffffu) : ~u;
    return __uint_as_float(v);
}
__device__ __forceinline__ unsigned short bf16_rne(float f) {
    unsigned u = __float_as_uint(f);
    u += 0x7fffu + ((u >> 16) & 1u);
    return (unsigned short)(u >> 16);
}
__device__ __forceinline__ float bf16_to_f(unsigned short h) {
    return __uint_as_float(((unsigned)h) << 16);
}

// numpy pairwise_sum over 64 squared elements (exact np emulation)
__device__ __forceinline__ float np_pairwise_sq64(const float* v) {
    float r[8];
#pragma unroll
    for (int j = 0; j < 8; j++) r[j] = __fmul_rn(v[j], v[j]);
#pragma unroll
    for (int i = 8; i < 64; i += 8) {
#pragma unroll
        for (int j = 0; j < 8; j++)
            r[j] = __fadd_rn(r[j], __fmul_rn(v[i + j], v[i + j]));
    }
    return __fadd_rn(__fadd_rn(__fadd_rn(r[0], r[1]), __fadd_rn(r[2], r[3])),
                     __fadd_rn(__fadd_rn(r[4], r[5]), __fadd_rn(r[6], r[7])));
}

// ---------------- kernel 0: wsq[k] = ||w_k||^2, np-exact fp32 ----------------
__global__ __launch_bounds__(256) void vq_wsq(const float* __restrict__ weight,
                                              float* __restrict__ wsq) {
    int k = blockIdx.x * 256 + threadIdx.x;
    float w[64];
    const float4* wp = (const float4*)(weight + (size_t)k * DIM);
#pragma unroll
    for (int i = 0; i < 16; i++) {
        float4 t = wp[i];
        w[4 * i] = t.x; w[4 * i + 1] = t.y; w[4 * i + 2] = t.z; w[4 * i + 3] = t.w;
    }
    wsq[k] = np_pairwise_sq64(w);
}

// ---------------- kernel 0b: pack weight into MFMA B-fragment order ----------
// Layout: [tile(512)][frag(4)][lane(64)] x 16B, frag: 0=hi_k0 1=hi_k32 2=lo_k0 3=lo_k32
// B-frag (16x16x32): lane holds B[k=(lane>>4)*8+j][n=lane&15], bf16 x8.
__global__ __launch_bounds__(256) void vq_split_w(const float* __restrict__ weight,
                                                  int4* __restrict__ packedW) {
    int tile = blockIdx.x * 4 + (threadIdx.x >> 6);   // 0..511
    int lane = threadIdx.x & 63;
    int code = tile * 16 + (lane & 15);
    int kq = (lane >> 4) * 8;
    const float* wp = weight + (size_t)code * DIM;

    union { bf16x8 v; int4 q; } hi0, hi1, lo0, lo1;
#pragma unroll
    for (int j = 0; j < 8; j++) {
        float a = wp[kq + j];
        unsigned short ha = bf16_rne(a);
        hi0.v[j] = (short)ha;
        lo0.v[j] = (short)bf16_rne(a - bf16_to_f(ha));
        float b = wp[32 + kq + j];
        unsigned short hb = bf16_rne(b);
        hi1.v[j] = (short)hb;
        lo1.v[j] = (short)bf16_rne(b - bf16_to_f(hb));
    }
    size_t base = (size_t)tile * 4 * 64;
    packedW[base + 0 * 64 + lane] = hi0.q;
    packedW[base + 1 * 64 + lane] = hi1.q;
    packedW[base + 2 * 64 + lane] = lo0.q;
    packedW[base + 3 * 64 + lane] = lo1.q;
}

// ---------------- kernel 1: MFMA argmin top-2 over a 1024-code chunk ----------
// grid (256, KSPLIT) x 256. Block: 128 rows; wave: 32 rows (2 row-tiles).
__global__ __launch_bounds__(256) void vq_argmin_mfma(const float* __restrict__ inp,
                                                      const int4* __restrict__ packedW,
                                                      const float* __restrict__ wsq,
                                                      unsigned long long* __restrict__ bestk,
                                                      float* __restrict__ secd) {
    __shared__ int4 sB[1024];   // 16 KB: one group = 4 code-tiles x 4 frags x 64 lanes
    int wave = threadIdx.x >> 6;
    int lane = threadIdx.x & 63;
    int rbase = blockIdx.x * 128 + wave * 32;
    int kbase = blockIdx.y * KCHUNK;

    // A fragments from raw fp32 rows: lane holds A[m=lane&15][k=(lane>>4)*8+j]
    int kq = (lane >> 4) * 8;
    bf16x8 ah[2][2], al[2][2];   // [row-tile][k-chunk]
#pragma unroll
    for (int rt = 0; rt < 2; rt++) {
        const float* xp = inp + (size_t)(rbase + rt * 16 + (lane & 15)) * DIM;
#pragma unroll
        for (int kc = 0; kc < 2; kc++) {
            const float* xq = xp + kc * 32 + kq;
#pragma unroll
            for (int j = 0; j < 8; j++) {
                float a = xq[j];
                unsigned short h = bf16_rne(a);
                ah[rt][kc][j] = (short)h;
                al[rt][kc][j] = (short)bf16_rne(a - bf16_to_f(h));
            }
        }
    }

    float best[8], sec[8];
    int bidx[8];
#pragma unroll
    for (int s = 0; s < 8; s++) { best[s] = 3.402823466e+38f; sec[s] = 3.402823466e+38f; bidx[s] = 0; }

    int lane_code = kbase + (lane & 15);

    for (int g = 0; g < 16; g++) {
        // stage 4 code-tiles (16 KB), wave w stages tile w of the group
        const char* src = (const char*)packedW + ((size_t)(kbase >> 4) + g * 4 + wave) * 4096;
        char* dst = (char*)sB + wave * 4096;
#pragma unroll
        for (int i = 0; i < 4; i++) {
            __builtin_amdgcn_global_load_lds(
                (const __attribute__((address_space(1))) unsigned int*)(src + i * 1024 + lane * 16),
                (__attribute__((address_space(3))) unsigned int*)(dst + i * 1024),
                16, 0, 0);
        }
        __syncthreads();
#pragma unroll
        for (int t = 0; t < 4; t++) {
            const int4* bp = sB + t * 256;
            union { int4 q; bf16x8 v; } bh0, bh1, bl0, bl1;
            bh0.q = bp[0 * 64 + lane];
            bh1.q = bp[1 * 64 + lane];
            bl0.q = bp[2 * 64 + lane];
            bl1.q = bp[3 * 64 + lane];
            int code_cur = lane_code + g * 64 + t * 16;
            float wsqv = wsq[code_cur];
#pragma unroll
            for (int rt = 0; rt < 2; rt++) {
                f32x4 acc = {0.f, 0.f, 0.f, 0.f};
                acc = __builtin_amdgcn_mfma_f32_16x16x32_bf16(ah[rt][0], bh0.v, acc, 0, 0, 0);
                acc = __builtin_amdgcn_mfma_f32_16x16x32_bf16(ah[rt][1], bh1.v, acc, 0, 0, 0);
                acc = __builtin_amdgcn_mfma_f32_16x16x32_bf16(al[rt][0], bh0.v, acc, 0, 0, 0);
                acc = __builtin_amdgcn_mfma_f32_16x16x32_bf16(al[rt][1], bh1.v, acc, 0, 0, 0);
                acc = __builtin_amdgcn_mfma_f32_16x16x32_bf16(ah[rt][0], bl0.v, acc, 0, 0, 0);
                acc = __builtin_amdgcn_mfma_f32_16x16x32_bf16(ah[rt][1], bl1.v, acc, 0, 0, 0);
#pragma unroll
                for (int r = 0; r < 4; r++) {
                    float c = fmaf(-2.0f, acc[r], wsqv);
                    int s = rt * 4 + r;
                    bool lt = c < best[s];
                    sec[s] = fminf(sec[s], fmaxf(c, best[s]));
                    best[s] = fminf(best[s], c);
                    bidx[s] = lt ? code_cur : bidx[s];
                }
            }
        }
        __syncthreads();
    }

    // reduce across the 16 columns (lanes sharing lane>>4 group)
#pragma unroll
    for (int m = 1; m < 16; m <<= 1) {
#pragma unroll
        for (int s = 0; s < 8; s++) {
            float ob = __shfl_xor(best[s], m, 64);
            float os = __shfl_xor(sec[s], m, 64);
            int   oi = __shfl_xor(bidx[s], m, 64);
            float mx = fmaxf(best[s], ob);
            sec[s] = fminf(fminf(sec[s], os), mx);
            bool take = (ob < best[s]) || (ob == best[s] && oi < bidx[s]);
            best[s] = take ? ob : best[s];
            bidx[s] = take ? oi : bidx[s];
        }
    }
    if ((lane & 15) == 0) {
        int g4 = lane >> 4;
#pragma unroll
        for (int rt = 0; rt < 2; rt++)
#pragma unroll
            for (int r = 0; r < 4; r++) {
                int row = rbase + rt * 16 + g4 * 4 + r;
                int s = rt * 4 + r;
                unsigned long long key =
                    ((unsigned long long)f2u_ord(best[s]) << 32) | (unsigned)bidx[s];
                bestk[(size_t)blockIdx.y * N_ROWS + row] = key;
                secd [(size_t)blockIdx.y * N_ROWS + row] = sec[s];
            }
    }
}

// ---------------- kernel 2: merge chunks, flag near-ties ----------------
__global__ __launch_bounds__(256) void vq_merge(const unsigned long long* __restrict__ bestk,
                                                const float* __restrict__ secd,
                                                int* __restrict__ final_idx,
                                                int* __restrict__ recheck_rows,
                                                int* __restrict__ recheck_count) {
    int row = blockIdx.x * 256 + threadIdx.x;

    unsigned long long ks[KSPLIT];
#pragma unroll
    for (int c = 0; c < KSPLIT; c++) ks[c] = bestk[(size_t)c * N_ROWS + row];

    unsigned long long k1 = ks[0];
#pragma unroll
    for (int c = 1; c < KSPLIT; c++) k1 = (ks[c] < k1) ? ks[c] : k1;

    float d1 = u2f_ord((unsigned)(k1 >> 32));
    float d2 = 3.402823466e+38f;
#pragma unroll
    for (int c = 0; c < KSPLIT; c++) {
        if (ks[c] != k1) {
            float bd = u2f_ord((unsigned)(ks[c] >> 32));
            if (bd < d2) d2 = bd;
        }
        float sd = secd[(size_t)c * N_ROWS + row];
        if (sd < d2) d2 = sd;
    }

    final_idx[row] = (int)(k1 & 0xffffffffull);
    if (d2 - d1 < MARGIN) {
        int slot = atomicAdd(recheck_count, 1);
        recheck_rows[slot] = row;
    }
}

// ---------------- kernel 3: np-exact rescan of flagged rows ----------------
__global__ __launch_bounds__(256) void vq_recheck_np(const float* __restrict__ inp,
                                                     const float* __restrict__ weight,
                                                     const float* __restrict__ wsq,
                                                     const int* __restrict__ recheck_rows,
                                                     const int* __restrict__ recheck_count,
                                                     int* __restrict__ final_idx) {
    __shared__ float xs[DIM];
    __shared__ float x2s;
    __shared__ float rd[256];
    __shared__ int   ri[256];
    int tid = threadIdx.x;
    int cnt = *recheck_count;
    if (cnt > N_ROWS) cnt = N_ROWS;

    for (int li = blockIdx.x; li < cnt; li += gridDim.x) {
        int row = recheck_rows[li];
        if (tid < DIM) xs[tid] = inp[(size_t)row * DIM + tid];
        __syncthreads();
        if (tid == 0) x2s = np_pairwise_sq64(xs);
        __syncthreads();
        float x2 = x2s;

        float bd = 3.402823466e+38f;
        int bi = 0x7fffffff;
        for (int code = tid; code < K_CODES; code += 256) {
            const float* wp = weight + (size_t)code * DIM;
            float s = 0.f;
#pragma unroll
            for (int i = 0; i < DIM; i++) s = __builtin_fmaf(xs[i], wp[i], s);
            float t1 = __fadd_rn(x2, wsq[code]);
            float d  = __fsub_rn(t1, __fmul_rn(2.0f, s));
            if (d < bd) { bd = d; bi = code; }
        }
        rd[tid] = bd; ri[tid] = bi;
        __syncthreads();
        for (int s = 128; s > 0; s >>= 1) {
            if (tid < s) {
                if (rd[tid + s] < rd[tid] ||
                    (rd[tid + s] == rd[tid] && ri[tid + s] < ri[tid])) {
                    rd[tid] = rd[tid + s]; ri[tid] = ri[tid + s];
                }
            }
            __syncthreads();
        }
        if (tid == 0) final_idx[row] = ri[0];
        __syncthreads();
    }
}

// ---------------- kernel 4: gather + STE + loss + index write ----------------
__global__ __launch_bounds__(256) void vq_final(const float* __restrict__ inp,
                                                const float* __restrict__ weight,
                                                const int* __restrict__ final_idx,
                                                float* __restrict__ out) {
    int gid = blockIdx.x * 256 + threadIdx.x;
    int row = gid >> 4;
    int sub = gid & 15;

    int idx = final_idx[row];

    float4 x = ((const float4*)inp)[gid];
    float4 w = ((const float4*)weight)[idx * 16 + sub];

    float4 q;
    q.x = x.x + (w.x - x.x);
    q.y = x.y + (w.y - x.y);
    q.z = x.z + (w.z - x.z);
    q.w = x.w + (w.w - x.w);
    ((float4*)(out + OUT_Q))[gid] = q;

    if (sub == 0) out[OUT_IDX + row] = (float)idx;

    float dx = w.x - x.x, dy = w.y - x.y, dz = w.z - x.z, dw = w.w - x.w;
    float lp = dx * dx + dy * dy + dz * dz + dw * dw;

#pragma unroll
    for (int o = 32; o > 0; o >>= 1) lp += __shfl_down(lp, o, 64);

    __shared__ float red[4];
    int wid = threadIdx.x >> 6;
    int lane = threadIdx.x & 63;
    if (lane == 0) red[wid] = lp;
    __syncthreads();
    if (threadIdx.x == 0) {
        float bs = red[0] + red[1] + red[2] + red[3];
        atomicAdd(out + OUT_LOSS, bs * (0.25f / 2097152.f));
    }
}

extern "C" void kernel_launch(void* const* d_in, const int* in_sizes, int n_in,
                              void* d_out, int out_size, void* d_ws, size_t ws_size,
                              hipStream_t stream) {
    const float* inp = (const float*)d_in[0];
    const float* weight = (const float*)d_in[1];
    float* out = (float*)d_out;

    char* ws = (char*)d_ws;
    unsigned long long* bestk = (unsigned long long*)ws;              // 2 MB
    float* secd      = (float*)(ws + (size_t)KSPLIT * N_ROWS * 8);    // 1 MB
    char*  p         = ws + (size_t)KSPLIT * N_ROWS * 12;
    int*   final_idx = (int*)p;                                       // 128 KB
    int*   rrows     = (int*)(p + (size_t)N_ROWS * 4);                // 128 KB
    int*   rcount    = (int*)(p + (size_t)N_ROWS * 8);                // 256 B
    float* wsq       = (float*)(p + (size_t)N_ROWS * 8 + 256);        // 32 KB
    int4*  packedW   = (int4*)(p + (size_t)N_ROWS * 8 + 256 + 32768); // 2 MB

    hipMemsetAsync(rcount, 0, sizeof(int), stream);
    hipMemsetAsync(out + OUT_LOSS, 0, sizeof(float), stream);

    vq_wsq<<<K_CODES / 256, 256, 0, stream>>>(weight, wsq);
    vq_split_w<<<128, 256, 0, stream>>>(weight, packedW);
    vq_argmin_mfma<<<dim3(N_ROWS / 128, KSPLIT), 256, 0, stream>>>(inp, packedW, wsq, bestk, secd);
    vq_merge<<<N_ROWS / 256, 256, 0, stream>>>(bestk, secd, final_idx, rrows, rcount);
    vq_recheck_np<<<64, 256, 0, stream>>>(inp, weight, wsq, rrows, rcount, final_idx);
    vq_final<<<(N_ROWS * DIM / 4) / 256, 256, 0, stream>>>(inp, weight, final_idx, out);
}